// Round 1
// baseline (352.416 us; speedup 1.0000x reference)
//
#include <hip/hip_runtime.h>
#include <stdint.h>

// Problem constants (fixed by the reference)
#define N_TOK 8192
#define IN_F 4096
#define OUT_F 4096
#define BS 256
#define ABPI 5
#define NFLAT 80          // 16 output blocks x 5 slots = all (g,a) pairs

typedef __attribute__((ext_vector_type(8))) short short8;    // 8 bf16 = 4 VGPRs (MFMA A/B frag)
typedef __attribute__((ext_vector_type(4))) float floatx4;   // MFMA C/D frag
typedef __attribute__((ext_vector_type(4))) unsigned short ushort4v;
typedef __attribute__((ext_vector_type(8))) unsigned short ushort8v;

__device__ __forceinline__ unsigned short f2bf(float f) {
  union { float f; unsigned int u; } v; v.f = f;
  unsigned int r = v.u + 0x7FFFu + ((v.u >> 16) & 1u);   // RNE
  return (unsigned short)(r >> 16);
}

__device__ __forceinline__ void async16(const void* g, void* l) {
  // per-lane global addr; LDS dst = wave-uniform base + lane*16 (our mapping is tid-contiguous)
  __builtin_amdgcn_global_load_lds((const __attribute__((address_space(1))) void*)g,
                                   (__attribute__((address_space(3))) void*)l, 16, 0, 0);
}

// ---------------- kernel 1: x fp32 -> bf16 ----------------
__global__ void cvt_x_kernel(const float4* __restrict__ x, ushort8v* __restrict__ xb) {
  int idx = blockIdx.x * 256 + threadIdx.x;   // one ushort8 (8 elems) per thread
  float4 a = x[idx * 2], b = x[idx * 2 + 1];
  ushort8v o;
  o[0] = f2bf(a.x); o[1] = f2bf(a.y); o[2] = f2bf(a.z); o[3] = f2bf(a.w);
  o[4] = f2bf(b.x); o[5] = f2bf(b.y); o[6] = f2bf(b.z); o[7] = f2bf(b.w);
  xb[idx] = o;
}

// ---------------- kernel 2: weight fp32 -> bf16, transposed per (g,a) block ----
// weight[(g*256+k)*1280 + a*256 + o]  ->  wt[(g*5+a)*65536 + o*256 + k]
__global__ void cvt_w_kernel(const float* __restrict__ w, unsigned short* __restrict__ wt) {
  __shared__ unsigned short tile[64][68];   // [o][k], padded
  int b = blockIdx.x;                 // 80 * 16
  int fi = b >> 4;
  int t  = b & 15;
  int k0 = (t >> 2) * 64, o0 = (t & 3) * 64;
  int g = fi / ABPI, a = fi % ABPI;
  int tid = threadIdx.x;
  int tr = tid >> 4, tc = tid & 15;   // 16 float4 per 64-wide row
  #pragma unroll
  for (int i = 0; i < 4; ++i) {
    int k = k0 + i * 16 + tr;
    const float* src = w + (size_t)(g * 256 + k) * (ABPI * BS) + a * BS + o0 + tc * 4;
    float4 v = *(const float4*)src;
    tile[tc * 4 + 0][i * 16 + tr] = f2bf(v.x);
    tile[tc * 4 + 1][i * 16 + tr] = f2bf(v.y);
    tile[tc * 4 + 2][i * 16 + tr] = f2bf(v.z);
    tile[tc * 4 + 3][i * 16 + tr] = f2bf(v.w);
  }
  __syncthreads();
  #pragma unroll
  for (int i = 0; i < 4; ++i) {
    int o = i * 16 + tr;
    unsigned short* dst = wt + (size_t)fi * (BS * BS) + (size_t)(o0 + o) * BS + k0 + tc * 4;
    *(ushort4v*)dst = *(const ushort4v*)&tile[o][tc * 4];
  }
}

// ---------------- kernel 3: butterfly block-sparse GEMM -------------------
// C[8192 x 4096] = sum over gathered K. Per block: 128x128 tile, K=1280 in BK=64 chunks.
// LDS As[m 128][k 64] bf16, Bs[n 128][k 64] bf16; chunk-XOR swizzle on the global side
// of global_load_lds so fragment ds_read_b128s are 2-way-bank (free).
__global__ __launch_bounds__(256, 2)
void bfly_gemm(const unsigned short* __restrict__ xb,   // [8192][4096] bf16
               const unsigned short* __restrict__ wt,   // [80][256 o][256 k] bf16
               const int* __restrict__ fidx,            // [16][5]
               float* __restrict__ out)                 // [8192][4096] fp32
{
  __shared__ __align__(16) short As[128 * 64];
  __shared__ __align__(16) short Bs[128 * 64];

  const int tid = threadIdx.x;
  const int bx  = blockIdx.x;          // 2048 blocks: [ob 16][mtile 64][nh 2]
  const int ob  = bx >> 7;
  const int rem = bx & 127;
  const int m0  = (rem >> 1) * 128;
  const int nh  = rem & 1;
  const int n0g = ob * 256 + nh * 128;

  int wbase[ABPI], gcol[ABPI];
  #pragma unroll
  for (int s = 0; s < ABPI; ++s) {
    int fi = fidx[ob * ABPI + s];      // fi = g*5 + a
    wbase[s] = fi * (BS * BS);
    gcol[s]  = (fi / ABPI) * BS;       // g*256: column base in x
  }

  // staging constants: LDS byte off = tid*16 + issue*4096 -> row sr+32i, chunk sc
  const int sr = tid >> 3;
  const int sc = tid & 7;
  const int lc = sc ^ (sr & 7);        // logical k-chunk held at this physical slot
  const size_t aBase = (size_t)(m0 + sr) * IN_F + lc * 8;
  const int    bBase = (nh * 128 + sr) * BS + lc * 8;
  short* aDst = As + tid * 8;
  short* bDst = Bs + tid * 8;

  // fragment-read constants
  const int lane = tid & 63;
  const int wv   = tid >> 6;
  const int wm   = (wv & 1) * 64;
  const int wn   = (wv >> 1) * 64;
  const int lrow = lane & 15;          // m (A) / n (B) within 16-tile
  const int quad = lane >> 4;          // k-group

  floatx4 acc[4][4] = {};

  for (int c = 0; c < 20; ++c) {       // K = 1280 = 20 * 64
    const int s  = c >> 2;
    const int kk = (c & 3) * 64;
    const unsigned short* aG = xb + aBase + gcol[s] + kk;
    const unsigned short* bG = wt + wbase[s] + bBase + kk;
    __syncthreads();                   // protect LDS still being read
    #pragma unroll
    for (int i = 0; i < 4; ++i) {
      async16(aG + (size_t)i * 32 * IN_F, aDst + i * 2048);
      async16(bG + i * 32 * BS,           bDst + i * 2048);
    }
    __syncthreads();                   // drains vmcnt -> staged data visible
    #pragma unroll
    for (int ks = 0; ks < 2; ++ks) {
      short8 af[4], bf[4];
      const int ch = ((ks * 4 + quad) ^ (lrow & 7)) * 8;
      #pragma unroll
      for (int mt = 0; mt < 4; ++mt)
        af[mt] = *(const short8*)(As + (wm + mt * 16 + lrow) * 64 + ch);
      #pragma unroll
      for (int nt = 0; nt < 4; ++nt)
        bf[nt] = *(const short8*)(Bs + (wn + nt * 16 + lrow) * 64 + ch);
      #pragma unroll
      for (int mt = 0; mt < 4; ++mt)
        #pragma unroll
        for (int nt = 0; nt < 4; ++nt)
          acc[mt][nt] = __builtin_amdgcn_mfma_f32_16x16x32_bf16(af[mt], bf[nt], acc[mt][nt], 0, 0, 0);
    }
  }

  // epilogue: C/D layout col=lane&15, row=quad*4+reg (m89-verified)
  #pragma unroll
  for (int mt = 0; mt < 4; ++mt) {
    const int rbase = m0 + wm + mt * 16 + quad * 4;
    #pragma unroll
    for (int nt = 0; nt < 4; ++nt) {
      const int col = n0g + wn + nt * 16 + lrow;
      float* po = out + (size_t)rbase * OUT_F + col;
      #pragma unroll
      for (int r = 0; r < 4; ++r)
        po[(size_t)r * OUT_F] = acc[mt][nt][r];
    }
  }
}

extern "C" void kernel_launch(void* const* d_in, const int* in_sizes, int n_in,
                              void* d_out, int out_size, void* d_ws, size_t ws_size,
                              hipStream_t stream) {
  const float* x  = (const float*)d_in[0];          // [8192][4096]
  const float* w  = (const float*)d_in[1];          // [4096][5][256]
  const int* fidx = (const int*)d_in[2];            // [16][5]
  float* out = (float*)d_out;

  // workspace: xb (64 MiB bf16) then wt (10 MiB bf16) = 74 MiB total
  unsigned short* xb = (unsigned short*)d_ws;
  unsigned short* wt = xb + (size_t)N_TOK * IN_F;

  cvt_x_kernel<<<(N_TOK * IN_F) / (8 * 256), 256, 0, stream>>>((const float4*)x, (ushort8v*)xb);
  cvt_w_kernel<<<NFLAT * 16, 256, 0, stream>>>(w, wt);
  bfly_gemm<<<16 * 64 * 2, 256, 0, stream>>>(xb, wt, fidx, out);
}